// Round 13
// baseline (260.224 us; speedup 1.0000x reference)
//
#include <hip/hip_runtime.h>
#include <hip/hip_bf16.h>
#include <stdint.h>

#define CONF_T 0.05f
#define KSEL 1000
#define CAND_CAP 2048
#define NWAVES 16

// Exact argmax/max over C classes for one anchor row (first-max-wins).
__device__ __forceinline__ void argmax_row(const float* __restrict__ probs, size_t row, int C,
                                           float& best, int& bcls)
{
    const float4* p = reinterpret_cast<const float4*>(probs + row * (size_t)C);
    float b = -1e30f; int c = 0;
    int q4 = C >> 2;
    for (int q = 0; q < q4; ++q) {
        float4 v = p[q];
        if (v.x > b) { b = v.x; c = 4*q + 0; }
        if (v.y > b) { b = v.y; c = 4*q + 1; }
        if (v.z > b) { b = v.z; c = 4*q + 2; }
        if (v.w > b) { b = v.w; c = 4*q + 3; }
    }
    best = b; bcls = c;
}

// ---------------- Kernel 1: per-anchor max/argmax over C classes ----------------
__global__ __launch_bounds__(256) void score_argmax_kernel(
    const float* __restrict__ probs, float* __restrict__ sc, int* __restrict__ cls,
    int total, int C)
{
    int gid = blockIdx.x * blockDim.x + threadIdx.x;
    if (gid >= total) return;
    float best; int bc;
    argmax_row(probs, (size_t)gid, C, best, bc);
    sc[gid]  = best;
    cls[gid] = bc;
}

// ---------------- Kernel 2: per-batch radix-select + rank-ordered top-K ----------------
// OUTPUTS ARE FLOAT32 (R12 forensics: harness reads d_out as f32[72000]).
// Layout: anchor_idxes (b,idx) [B,K,2] | boxes [B,K,4] | cls [B,K] | scores [B,K] | valid [B,K].
// Ties: ascending index (lax.top_k semantics).
__global__ __launch_bounds__(1024) void topk_select_kernel(
    const float* __restrict__ sc_ws, const int* __restrict__ cls_ws,
    const float* __restrict__ probs,
    const float* __restrict__ anchors, const float* __restrict__ offsets,
    const float* __restrict__ window, float* __restrict__ out,
    int N, int C, int B)
{
    const int b   = blockIdx.x;
    const int tid = threadIdx.x;
    const int wav = tid >> 6;
    const bool use_ws = (sc_ws != nullptr);

    __shared__ uint32_t hw[NWAVES][256];
    __shared__ uint32_t histT[256];
    __shared__ uint32_t sh_prefix, sh_rem, sh_cnt;
    __shared__ uint64_t cand[CAND_CAP];

    if (tid == 0) { sh_prefix = 0u; sh_rem = KSEL; sh_cnt = 0u; }
    __syncthreads();

    // ---- 4-pass MSB->LSB byte radix select on raw f32 bits (scores >= 0 -> monotone)
    for (int pass = 0; pass < 4; ++pass) {
        const int shift = 24 - 8 * pass;
        for (int i = tid; i < NWAVES * 256; i += 1024)
            (&hw[0][0])[i] = 0u;
        __syncthreads();
        const uint32_t pref = sh_prefix;
        const uint32_t hs = (pass == 0) ? 31u : (uint32_t)(shift + 8);
        for (int i = tid; i < N; i += 1024) {
            uint32_t bits;
            if (use_ws) bits = __float_as_uint(sc_ws[(size_t)b * N + i]);
            else { float s; int c; argmax_row(probs, (size_t)b * N + i, C, s, c); bits = __float_as_uint(s); }
            bool ok = (pass == 0) || ((bits >> hs) == (pref >> hs));
            if (ok) atomicAdd(&hw[wav][(bits >> shift) & 255u], 1u);
        }
        __syncthreads();
        if (tid < 256) {
            uint32_t s = 0;
            for (int wv = 0; wv < NWAVES; ++wv) s += hw[wv][tid];
            histT[tid] = s;
        }
        __syncthreads();
        if (tid == 0) {
            uint32_t rem = sh_rem, cum = 0;
            int v;
            for (v = 255; v >= 0; --v) { cum += histT[v]; if (cum >= rem) break; }
            if (v < 0) v = 0;
            sh_rem    = rem - (cum - histT[v]);
            sh_prefix = pref | ((uint32_t)v << shift);
        }
        __syncthreads();
    }
    const uint32_t tbits = sh_prefix;   // bit pattern of the K-th largest score

    // ---- gather candidates with score >= t
    for (int i = tid; i < N; i += 1024) {
        uint32_t bits;
        if (use_ws) bits = __float_as_uint(sc_ws[(size_t)b * N + i]);
        else { float s; int c; argmax_row(probs, (size_t)b * N + i, C, s, c); bits = __float_as_uint(s); }
        if (bits >= tbits) {
            uint32_t pos = atomicAdd(&sh_cnt, 1u);
            if (pos < CAND_CAP)
                cand[pos] = ((uint64_t)(~bits) << 32) | (uint64_t)(uint32_t)i;  // ties: ASC idx
        }
    }
    __syncthreads();
    uint32_t G = sh_cnt;
    if (G > CAND_CAP) G = CAND_CAP;

    // ---- exact rank; distinct keys -> each output slot written once
    const float wy1 = window[0], wx1 = window[1], wy2 = window[2], wx2 = window[3];
    const int BK = B * KSEL;
    float* o_ai = out;             // [B,K,2] (b, idx)
    float* o_bx = out + 2 * BK;    // [B,K,4] boxes
    float* o_cl = out + 6 * BK;    // [B,K]   class ids
    float* o_sc = out + 7 * BK;    // [B,K]   scores
    float* o_vd = out + 8 * BK;    // [B,K]   valid

    for (uint32_t c = tid; c < G; c += 1024) {
        const uint64_t kc = cand[c];
        uint32_t r = 0;
        for (uint32_t j = 0; j < G; ++j) r += (cand[j] < kc) ? 1u : 0u;
        if (r >= KSEL) continue;

        uint32_t idx   = (uint32_t)kc;
        uint32_t sbits = ~(uint32_t)(kc >> 32);
        float score    = __uint_as_float(sbits);

        size_t base = (size_t)b * N + idx;
        int cv;
        if (use_ws) cv = cls_ws[base];
        else { float s2; argmax_row(probs, base, C, s2, cv); }

        const float4 a = *reinterpret_cast<const float4*>(anchors + base * 4);
        const float4 o = *reinterpret_cast<const float4*>(offsets + base * 4);

        float h  = a.z - a.x;
        float w  = a.w - a.y;
        float cy = a.x + 0.5f * h + o.x * h;
        float cx = a.y + 0.5f * w + o.y * w;
        float hh = h * expf(o.z);
        float ww = w * expf(o.w);
        float y1 = cy - 0.5f * hh, x1 = cx - 0.5f * ww;
        float y2 = cy + 0.5f * hh, x2 = cx + 0.5f * ww;
        y1 = fminf(fmaxf(y1, wy1), wy2);
        y2 = fminf(fmaxf(y2, wy1), wy2);
        x1 = fminf(fmaxf(x1, wx1), wx2);
        x2 = fminf(fmaxf(x2, wx1), wx2);

        int ok = b * KSEL + (int)r;
        o_ai[ok*2 + 0] = (float)b;
        o_ai[ok*2 + 1] = (float)idx;
        o_bx[ok*4 + 0] = y1;
        o_bx[ok*4 + 1] = x1;
        o_bx[ok*4 + 2] = y2;
        o_bx[ok*4 + 3] = x2;
        o_cl[ok] = (float)cv;
        o_sc[ok] = score;
        o_vd[ok] = (score > CONF_T) ? 1.0f : 0.0f;
    }
}

extern "C" void kernel_launch(void* const* d_in, const int* in_sizes, int n_in,
                              void* d_out, int out_size, void* d_ws, size_t ws_size,
                              hipStream_t stream)
{
    const float* anchors = (const float*)d_in[0];
    const float* probs   = (const float*)d_in[1];
    const float* offsets = (const float*)d_in[2];
    const float* window  = (const float*)d_in[3];

    const int B = out_size / (9 * KSEL);
    const int N = in_sizes[0] / (B * 4);
    const int C = in_sizes[1] / (B * N);
    const int total = B * N;

    const size_t need = (size_t)total * (sizeof(float) + sizeof(int));
    const bool use_ws = (d_ws != nullptr) && (ws_size >= need);

    float* sc  = nullptr;
    int*   cls = nullptr;
    if (use_ws) {
        sc  = (float*)d_ws;
        cls = (int*)((char*)d_ws + (size_t)total * sizeof(float));
        hipLaunchKernelGGL(score_argmax_kernel, dim3((total + 255) / 256), dim3(256), 0, stream,
                           probs, sc, cls, total, C);
    }

    hipLaunchKernelGGL(topk_select_kernel, dim3(B), dim3(1024), 0, stream,
                       sc, cls, probs, anchors, offsets, window,
                       (float*)d_out, N, C, B);
}

// Round 14
// 173.597 us; speedup vs baseline: 1.4990x; 1.4990x over previous
//
#include <hip/hip_runtime.h>
#include <hip/hip_bf16.h>
#include <stdint.h>

#define CONF_T 0.05f
#define KSEL 1000
#define CAND_CAP 2048
#define ROWS 128      // rows per block in kernel 1
#define T1 256        // kernel-1 block size

// ---------------- Kernel 1: LDS-staged coalesced score/argmax ----------------
// Each block stages ROWS rows (ROWS*C floats) into LDS via fully-coalesced float4
// loads, then thread t reduces row t (padded stride 81 -> conflict-free).
__global__ __launch_bounds__(T1) void score_argmax_kernel(
    const float* __restrict__ probs, float* __restrict__ sc, int* __restrict__ cls,
    int total, int C)
{
    __shared__ float tile[ROWS * 81];
    const int r0  = blockIdx.x * ROWS;
    const int tid = threadIdx.x;
    const int rows_here = min(ROWS, total - r0);

    const float4* src = reinterpret_cast<const float4*>(probs + (size_t)r0 * C);
    const int nf4 = rows_here * C / 4;     // C % 4 == 0
    for (int f = tid; f < nf4; f += T1) {
        float4 v = src[f];
        int fo  = f * 4;
        int row = fo / 80;                 // C == 80 for this problem
        int col = fo - row * 80;
        float* dst = &tile[row * 81 + col];
        dst[0] = v.x; dst[1] = v.y; dst[2] = v.z; dst[3] = v.w;
    }
    __syncthreads();

    if (tid < rows_here) {
        const float* row = &tile[tid * 81];
        float best = row[0]; int bc = 0;
        #pragma unroll
        for (int j = 1; j < 80; ++j) {
            float v = row[j];
            if (v > best) { best = v; bc = j; }   // first-max-wins
        }
        sc[r0 + tid]  = best;
        cls[r0 + tid] = bc;
    }
}

// Wave-aggregated histogram add: group identical byte values (ballot), leader adds
// popcount. Bounded to 4 groups, then plain atomic fallback (for high-entropy passes).
__device__ __forceinline__ void hist_add(uint32_t* hist, uint32_t byteval, bool ok)
{
    const int lane = threadIdx.x & 63;
    unsigned long long remaining = __ballot(ok);
    int rounds = 0;
    while (remaining && rounds < 4) {
        int leader = __ffsll(remaining) - 1;
        uint32_t lv = __shfl(byteval, leader);
        unsigned long long eq = __ballot(ok && byteval == lv) & remaining;
        if (lane == leader) atomicAdd(&hist[lv], (uint32_t)__popcll(eq));
        remaining &= ~eq;
        ++rounds;
    }
    if (remaining && ok && (remaining >> lane) & 1ull)
        atomicAdd(&hist[byteval], 1u);
}

// ---------------- Kernel 2: per-batch radix-select + rank-ordered top-K ----------------
// f32 outputs: (b,idx)[B,K,2] | boxes[B,K,4] | cls | scores | valid. Ties: ascending idx.
__global__ __launch_bounds__(1024) void topk_select_kernel(
    const float* __restrict__ scores, const int* __restrict__ cls_ws,
    const float* __restrict__ anchors, const float* __restrict__ offsets,
    const float* __restrict__ window, float* __restrict__ out,
    int N, int B)
{
    const int b   = blockIdx.x;
    const int tid = threadIdx.x;

    const float4* s4 = reinterpret_cast<const float4*>(scores + (size_t)b * N);
    const int n4 = N >> 2;   // N % 4 == 0

    __shared__ uint32_t hist[256];
    __shared__ uint32_t sh_prefix, sh_rem, sh_cnt;
    __shared__ uint64_t cand[CAND_CAP];

    if (tid == 0) { sh_prefix = 0u; sh_rem = KSEL; sh_cnt = 0u; }
    __syncthreads();

    // ---- 4-pass MSB->LSB byte radix select on raw f32 bits (scores >= 0 -> monotone)
    for (int pass = 0; pass < 4; ++pass) {
        const int shift = 24 - 8 * pass;
        if (tid < 256) hist[tid] = 0u;
        __syncthreads();
        const uint32_t pref = sh_prefix;
        const uint32_t hs = (pass == 0) ? 31u : (uint32_t)(shift + 8);
        for (int f = tid; f < n4; f += 1024) {
            float4 v = s4[f];
            #pragma unroll
            for (int j = 0; j < 4; ++j) {
                uint32_t bits = __float_as_uint(j==0 ? v.x : j==1 ? v.y : j==2 ? v.z : v.w);
                bool ok = (pass == 0) || ((bits >> hs) == (pref >> hs));
                hist_add(hist, (bits >> shift) & 255u, ok);
            }
        }
        __syncthreads();
        if (tid == 0) {
            uint32_t rem = sh_rem, cum = 0;
            int v;
            for (v = 255; v >= 0; --v) { cum += hist[v]; if (cum >= rem) break; }
            if (v < 0) v = 0;
            sh_rem    = rem - (cum - hist[v]);
            sh_prefix = pref | ((uint32_t)v << shift);
        }
        __syncthreads();
    }
    const uint32_t tbits = sh_prefix;   // bit pattern of the K-th largest score

    // ---- gather candidates with score >= t
    for (int f = tid; f < n4; f += 1024) {
        float4 v = s4[f];
        #pragma unroll
        for (int j = 0; j < 4; ++j) {
            uint32_t bits = __float_as_uint(j==0 ? v.x : j==1 ? v.y : j==2 ? v.z : v.w);
            if (bits >= tbits) {
                uint32_t pos = atomicAdd(&sh_cnt, 1u);
                if (pos < CAND_CAP)
                    cand[pos] = ((uint64_t)(~bits) << 32) | (uint64_t)(uint32_t)(4*f + j);
            }
        }
    }
    __syncthreads();
    uint32_t G = sh_cnt;
    if (G > CAND_CAP) G = CAND_CAP;

    // ---- exact rank (keys distinct); decode + f32 write
    const float wy1 = window[0], wx1 = window[1], wy2 = window[2], wx2 = window[3];
    const int BK = B * KSEL;
    float* o_ai = out;             // [B,K,2] (b, idx)
    float* o_bx = out + 2 * BK;    // [B,K,4]
    float* o_cl = out + 6 * BK;
    float* o_sc = out + 7 * BK;
    float* o_vd = out + 8 * BK;

    for (uint32_t c = tid; c < G; c += 1024) {
        const uint64_t kc = cand[c];
        uint32_t r = 0;
        for (uint32_t j = 0; j < G; ++j) r += (cand[j] < kc) ? 1u : 0u;
        if (r >= KSEL) continue;

        uint32_t idx   = (uint32_t)kc;
        uint32_t sbits = ~(uint32_t)(kc >> 32);
        float score    = __uint_as_float(sbits);

        size_t base = (size_t)b * N + idx;
        const float4 a = *reinterpret_cast<const float4*>(anchors + base * 4);
        const float4 o = *reinterpret_cast<const float4*>(offsets + base * 4);

        float h  = a.z - a.x;
        float w  = a.w - a.y;
        float cy = a.x + 0.5f * h + o.x * h;
        float cx = a.y + 0.5f * w + o.y * w;
        float hh = h * expf(o.z);
        float ww = w * expf(o.w);
        float y1 = fminf(fmaxf(cy - 0.5f * hh, wy1), wy2);
        float x1 = fminf(fmaxf(cx - 0.5f * ww, wx1), wx2);
        float y2 = fminf(fmaxf(cy + 0.5f * hh, wy1), wy2);
        float x2 = fminf(fmaxf(cx + 0.5f * ww, wx1), wx2);

        int ok = b * KSEL + (int)r;
        o_ai[ok*2 + 0] = (float)b;
        o_ai[ok*2 + 1] = (float)idx;
        o_bx[ok*4 + 0] = y1;
        o_bx[ok*4 + 1] = x1;
        o_bx[ok*4 + 2] = y2;
        o_bx[ok*4 + 3] = x2;
        o_cl[ok] = (float)cls_ws[base];
        o_sc[ok] = score;
        o_vd[ok] = (score > CONF_T) ? 1.0f : 0.0f;
    }
}

extern "C" void kernel_launch(void* const* d_in, const int* in_sizes, int n_in,
                              void* d_out, int out_size, void* d_ws, size_t ws_size,
                              hipStream_t stream)
{
    const float* anchors = (const float*)d_in[0];
    const float* probs   = (const float*)d_in[1];
    const float* offsets = (const float*)d_in[2];
    const float* window  = (const float*)d_in[3];

    const int B = out_size / (9 * KSEL);
    const int N = in_sizes[0] / (B * 4);
    const int total = B * N;

    float* sc  = (float*)d_ws;
    int*   cls = (int*)((char*)d_ws + (size_t)total * sizeof(float));

    hipLaunchKernelGGL(score_argmax_kernel,
                       dim3((total + ROWS - 1) / ROWS), dim3(T1), 0, stream,
                       probs, sc, cls, total, 80);

    hipLaunchKernelGGL(topk_select_kernel, dim3(B), dim3(1024), 0, stream,
                       sc, cls, anchors, offsets, window,
                       (float*)d_out, N, B);
}

// Round 15
// 139.237 us; speedup vs baseline: 1.8689x; 1.2468x over previous
//
#include <hip/hip_runtime.h>
#include <hip/hip_bf16.h>
#include <stdint.h>

#define CONF_T 0.05f
#define KSEL 1000
#define CAND_CAP 2048
#define ROWS 128
#define T1 256
#define NPASS 4
#define CHUNK 2048    // elements per hist block

// ---------------- Kernel 1: LDS-staged coalesced score/argmax (unchanged, ~roofline) ----
__global__ __launch_bounds__(T1) void score_argmax_kernel(
    const float* __restrict__ probs, float* __restrict__ sc, int* __restrict__ cls,
    int total, int C)
{
    __shared__ float tile[ROWS * 81];
    const int r0  = blockIdx.x * ROWS;
    const int tid = threadIdx.x;
    const int rows_here = min(ROWS, total - r0);

    const float4* src = reinterpret_cast<const float4*>(probs + (size_t)r0 * C);
    const int nf4 = rows_here * C / 4;
    for (int f = tid; f < nf4; f += T1) {
        float4 v = src[f];
        int fo  = f * 4;
        int row = fo / 80;
        int col = fo - row * 80;
        float* dst = &tile[row * 81 + col];
        dst[0] = v.x; dst[1] = v.y; dst[2] = v.z; dst[3] = v.w;
    }
    __syncthreads();

    if (tid < rows_here) {
        const float* row = &tile[tid * 81];
        float best = row[0]; int bc = 0;
        #pragma unroll
        for (int j = 1; j < 80; ++j) {
            float v = row[j];
            if (v > best) { best = v; bc = j; }
        }
        sc[r0 + tid]  = best;
        cls[r0 + tid] = bc;
    }
}

__global__ void zero_hist_kernel(uint32_t* __restrict__ hist_g, int n)
{
    int gid = blockIdx.x * blockDim.x + threadIdx.x;
    if (gid < n) hist_g[gid] = 0u;
}

// Rebuild (prefix, rem) from passes [0, upto) using global per-batch histograms.
// All threads exit with identical pref/rem. Needs shared ph[256] + sh2[2].
__device__ __forceinline__ void reconstruct(
    const uint32_t* __restrict__ hist_g, int b, int upto,
    uint32_t& pref, uint32_t& rem, uint32_t* ph, uint32_t* sh2)
{
    pref = 0u; rem = KSEL;
    for (int q = 0; q < upto; ++q) {
        if (threadIdx.x < 256) ph[threadIdx.x] = hist_g[(size_t)(b * NPASS + q) * 256 + threadIdx.x];
        __syncthreads();
        if (threadIdx.x == 0) {
            uint32_t cum = 0; int v;
            for (v = 255; v >= 0; --v) { cum += ph[v]; if (cum >= rem) break; }
            if (v < 0) v = 0;
            sh2[0] = pref | ((uint32_t)v << (24 - 8 * q));
            sh2[1] = rem - (cum - ph[v]);
        }
        __syncthreads();
        pref = sh2[0]; rem = sh2[1];
        __syncthreads();
    }
}

// ---------------- Histogram pass kernel (grid-parallel radix select) ----------------
template <int PASS>
__global__ __launch_bounds__(256) void hist_pass_kernel(
    const float* __restrict__ scores, uint32_t* __restrict__ hist_g, int N, int nchunks)
{
    const int b     = blockIdx.x / nchunks;
    const int chunk = blockIdx.x % nchunks;
    const int tid   = threadIdx.x;

    __shared__ uint32_t ph[256];
    __shared__ uint32_t sh2[2];
    __shared__ uint32_t lh[256];

    uint32_t pref, rem;
    reconstruct(hist_g, b, PASS, pref, rem, ph, sh2);

    if (tid < 256) lh[tid] = 0u;
    __syncthreads();

    const int shift = 24 - 8 * PASS;
    const uint32_t hs = (PASS == 0) ? 31u : (uint32_t)(shift + 8);
    const float4* s4 = reinterpret_cast<const float4*>(scores + (size_t)b * N);

    const int f_beg = (chunk * CHUNK) >> 2;
    const int f_end = min((chunk + 1) * CHUNK, N) >> 2;

    // per-thread run aggregation (degenerate bytes -> ~1 LDS atomic per thread)
    uint32_t curb = 0xFFFFFFFFu, cnt = 0;
    for (int f = f_beg + tid; f < f_end; f += 256) {
        float4 v = s4[f];
        #pragma unroll
        for (int j = 0; j < 4; ++j) {
            uint32_t bits = __float_as_uint(j==0 ? v.x : j==1 ? v.y : j==2 ? v.z : v.w);
            bool ok = (PASS == 0) || ((bits >> hs) == (pref >> hs));
            if (ok) {
                uint32_t byte = (bits >> shift) & 255u;
                if (byte == curb) ++cnt;
                else { if (cnt) atomicAdd(&lh[curb], cnt); curb = byte; cnt = 1u; }
            }
        }
    }
    if (cnt) atomicAdd(&lh[curb], cnt);
    __syncthreads();

    if (tid < 256 && lh[tid])
        atomicAdd(&hist_g[(size_t)(b * NPASS + PASS) * 256 + tid], lh[tid]);
}

// ---------------- Final: gather + exact rank + decode + f32 write ----------------
__global__ __launch_bounds__(1024) void final_select_kernel(
    const float* __restrict__ scores, const int* __restrict__ cls_ws,
    const uint32_t* __restrict__ hist_g,
    const float* __restrict__ anchors, const float* __restrict__ offsets,
    const float* __restrict__ window, float* __restrict__ out,
    int N, int B)
{
    const int b   = blockIdx.x;
    const int tid = threadIdx.x;

    __shared__ uint32_t ph[256];
    __shared__ uint32_t sh2[2];
    __shared__ uint32_t sh_cnt;
    __shared__ uint64_t cand[CAND_CAP];

    uint32_t tbits, rem;
    reconstruct(hist_g, b, NPASS, tbits, rem, ph, sh2);
    if (tid == 0) sh_cnt = 0u;
    __syncthreads();

    const float4* s4 = reinterpret_cast<const float4*>(scores + (size_t)b * N);
    const int n4 = N >> 2;
    for (int f = tid; f < n4; f += 1024) {
        float4 v = s4[f];
        #pragma unroll
        for (int j = 0; j < 4; ++j) {
            uint32_t bits = __float_as_uint(j==0 ? v.x : j==1 ? v.y : j==2 ? v.z : v.w);
            if (bits >= tbits) {
                uint32_t pos = atomicAdd(&sh_cnt, 1u);
                if (pos < CAND_CAP)
                    cand[pos] = ((uint64_t)(~bits) << 32) | (uint64_t)(uint32_t)(4*f + j);  // ties: ASC idx
            }
        }
    }
    __syncthreads();
    uint32_t G = sh_cnt;
    if (G > CAND_CAP) G = CAND_CAP;

    const float wy1 = window[0], wx1 = window[1], wy2 = window[2], wx2 = window[3];
    const int BK = B * KSEL;
    float* o_ai = out;             // [B,K,2] (b, idx)
    float* o_bx = out + 2 * BK;    // [B,K,4]
    float* o_cl = out + 6 * BK;
    float* o_sc = out + 7 * BK;
    float* o_vd = out + 8 * BK;

    for (uint32_t c = tid; c < G; c += 1024) {
        const uint64_t kc = cand[c];
        uint32_t r = 0;
        for (uint32_t j = 0; j < G; ++j) r += (cand[j] < kc) ? 1u : 0u;
        if (r >= KSEL) continue;

        uint32_t idx   = (uint32_t)kc;
        uint32_t sbits = ~(uint32_t)(kc >> 32);
        float score    = __uint_as_float(sbits);

        size_t base = (size_t)b * N + idx;
        const float4 a = *reinterpret_cast<const float4*>(anchors + base * 4);
        const float4 o = *reinterpret_cast<const float4*>(offsets + base * 4);

        float h  = a.z - a.x;
        float w  = a.w - a.y;
        float cy = a.x + 0.5f * h + o.x * h;
        float cx = a.y + 0.5f * w + o.y * w;
        float hh = h * expf(o.z);
        float ww = w * expf(o.w);
        float y1 = fminf(fmaxf(cy - 0.5f * hh, wy1), wy2);
        float x1 = fminf(fmaxf(cx - 0.5f * ww, wx1), wx2);
        float y2 = fminf(fmaxf(cy + 0.5f * hh, wy1), wy2);
        float x2 = fminf(fmaxf(cx + 0.5f * ww, wx1), wx2);

        int ok = b * KSEL + (int)r;
        o_ai[ok*2 + 0] = (float)b;
        o_ai[ok*2 + 1] = (float)idx;
        o_bx[ok*4 + 0] = y1;
        o_bx[ok*4 + 1] = x1;
        o_bx[ok*4 + 2] = y2;
        o_bx[ok*4 + 3] = x2;
        o_cl[ok] = (float)cls_ws[base];
        o_sc[ok] = score;
        o_vd[ok] = (score > CONF_T) ? 1.0f : 0.0f;
    }
}

extern "C" void kernel_launch(void* const* d_in, const int* in_sizes, int n_in,
                              void* d_out, int out_size, void* d_ws, size_t ws_size,
                              hipStream_t stream)
{
    const float* anchors = (const float*)d_in[0];
    const float* probs   = (const float*)d_in[1];
    const float* offsets = (const float*)d_in[2];
    const float* window  = (const float*)d_in[3];

    const int B = out_size / (9 * KSEL);
    const int N = in_sizes[0] / (B * 4);
    const int total = B * N;

    float*    sc     = (float*)d_ws;
    int*      cls    = (int*)((char*)d_ws + (size_t)total * sizeof(float));
    uint32_t* hist_g = (uint32_t*)((char*)d_ws + (size_t)total * 8);
    const int nhist  = B * NPASS * 256;

    hipLaunchKernelGGL(zero_hist_kernel, dim3((nhist + 255) / 256), dim3(256), 0, stream,
                       hist_g, nhist);

    hipLaunchKernelGGL(score_argmax_kernel,
                       dim3((total + ROWS - 1) / ROWS), dim3(T1), 0, stream,
                       probs, sc, cls, total, 80);

    const int nchunks = (N + CHUNK - 1) / CHUNK;
    dim3 hgrid(B * nchunks), hblk(256);
    hipLaunchKernelGGL(hist_pass_kernel<0>, hgrid, hblk, 0, stream, sc, hist_g, N, nchunks);
    hipLaunchKernelGGL(hist_pass_kernel<1>, hgrid, hblk, 0, stream, sc, hist_g, N, nchunks);
    hipLaunchKernelGGL(hist_pass_kernel<2>, hgrid, hblk, 0, stream, sc, hist_g, N, nchunks);
    hipLaunchKernelGGL(hist_pass_kernel<3>, hgrid, hblk, 0, stream, sc, hist_g, N, nchunks);

    hipLaunchKernelGGL(final_select_kernel, dim3(B), dim3(1024), 0, stream,
                       sc, cls, hist_g, anchors, offsets, window,
                       (float*)d_out, N, B);
}

// Round 16
// 114.354 us; speedup vs baseline: 2.2756x; 1.2176x over previous
//
#include <hip/hip_runtime.h>
#include <hip/hip_bf16.h>
#include <stdint.h>

#define CONF_T 0.05f
#define KSEL 1000
#define CAND_CAP 2048
#define ROWS 128
#define T1 256
#define SH_A 21          // pass-A window: bits[31:21] (11 bits)
#define SH_B 10          // pass-B window: bits[20:10] (11 bits)

// ---------------- Kernel 1: LDS-staged argmax + fused pass-A histogram ----------------
__global__ __launch_bounds__(T1) void score_argmax_hist_kernel(
    const float* __restrict__ probs, float* __restrict__ sc, int* __restrict__ cls,
    uint32_t* __restrict__ hist_g, int total, int N)
{
    __shared__ float tile[ROWS * 81];
    __shared__ uint32_t lh[2048];        // packed dual-batch: lo16 = b0, hi16 = b0+1
    const int r0  = blockIdx.x * ROWS;
    const int tid = threadIdx.x;
    const int rows_here = min(ROWS, total - r0);
    const int b0 = r0 / N;

    for (int i = tid; i < 2048; i += T1) lh[i] = 0u;

    const float4* src = reinterpret_cast<const float4*>(probs + (size_t)r0 * 80);
    const int nf4 = rows_here * 20;
    for (int f = tid; f < nf4; f += T1) {
        float4 v = src[f];
        int fo  = f * 4;
        int row = fo / 80;
        int col = fo - row * 80;
        float* dst = &tile[row * 81 + col];
        dst[0] = v.x; dst[1] = v.y; dst[2] = v.z; dst[3] = v.w;
    }
    __syncthreads();

    if (tid < rows_here) {
        const float* row = &tile[tid * 81];
        float best = row[0]; int bc = 0;
        #pragma unroll
        for (int j = 1; j < 80; ++j) {
            float v = row[j];
            if (v > best) { best = v; bc = j; }   // first-max-wins
        }
        const int gr = r0 + tid;
        sc[gr]  = best;
        cls[gr] = bc;
        const int sel = (gr / N) - b0;            // 0 or 1 (block straddles <= 2 batches)
        atomicAdd(&lh[__float_as_uint(best) >> SH_A], 1u << (16 * sel));
    }
    __syncthreads();

    for (int i = tid; i < 2048; i += T1) {
        uint32_t v = lh[i];
        if (v & 0xFFFFu) atomicAdd(&hist_g[(size_t)b0 * 2048 + i], v & 0xFFFFu);
        uint32_t hi = v >> 16;
        if (hi)          atomicAdd(&hist_g[(size_t)(b0 + 1) * 2048 + i], hi);
    }
}

// Find bin v (descending) where cumulative-from-top crosses rem; res = {v, rem_in_bin}.
__device__ __forceinline__ void hist_crossing(
    const uint32_t* __restrict__ hh, uint32_t* __restrict__ partial,
    volatile uint32_t* __restrict__ res, uint32_t rem)
{
    const int tid = threadIdx.x;
    if (tid < 256) {
        uint32_t s = 0;
        #pragma unroll
        for (int j = 0; j < 8; ++j) s += hh[tid * 8 + j];
        partial[tid] = s;
    }
    __syncthreads();
    if (tid == 0) {
        uint32_t cum = 0; int g;
        for (g = 255; g >= 0; --g) { cum += partial[g]; if (cum >= rem) break; }
        if (g < 0) g = 0;
        uint32_t cum2 = cum - partial[g]; int v = 8 * g;
        for (int j = 7; j >= 0; --j) {
            cum2 += hh[8 * g + j];
            if (cum2 >= rem) { v = 8 * g + j; break; }
        }
        res[0] = (uint32_t)v;
        res[1] = rem - (cum2 - hh[v]);
    }
    __syncthreads();
}

// ---------------- Kernel 2: pass-B hist + gather + exact rank + decode ----------------
__global__ __launch_bounds__(1024) void final_select_kernel(
    const float* __restrict__ scores, const int* __restrict__ cls_ws,
    const uint32_t* __restrict__ hist_g,
    const float* __restrict__ anchors, const float* __restrict__ offsets,
    const float* __restrict__ window, float* __restrict__ out,
    int N, int B)
{
    const int b   = blockIdx.x;
    const int tid = threadIdx.x;

    __shared__ uint32_t hh[2048];
    __shared__ uint32_t partial[256];
    __shared__ uint32_t resA[2], resB[2];
    __shared__ uint32_t sh_cnt;
    __shared__ uint64_t cand[CAND_CAP];

    // ---- pass-A crossing from global hist
    for (int i = tid; i < 2048; i += 1024) hh[i] = hist_g[(size_t)b * 2048 + i];
    if (tid == 0) sh_cnt = 0u;
    __syncthreads();
    hist_crossing(hh, partial, resA, KSEL);
    const uint32_t vA = resA[0], remA = resA[1];

    // ---- pass-B histogram (bits[20:10]) over elements matching prefix A
    for (int i = tid; i < 2048; i += 1024) hh[i] = 0u;
    __syncthreads();
    const float4* s4 = reinterpret_cast<const float4*>(scores + (size_t)b * N);
    const int n4 = N >> 2;
    for (int f = tid; f < n4; f += 1024) {
        float4 v = s4[f];
        #pragma unroll
        for (int j = 0; j < 4; ++j) {
            uint32_t bits = __float_as_uint(j==0 ? v.x : j==1 ? v.y : j==2 ? v.z : v.w);
            if ((bits >> SH_A) == vA)
                atomicAdd(&hh[(bits >> SH_B) & 0x7FFu], 1u);
        }
    }
    __syncthreads();
    hist_crossing(hh, partial, resB, remA);
    const uint32_t t_lo = (vA << SH_A) | (resB[0] << SH_B);   // lower bound on Kth score bits

    // ---- gather all candidates with bits >= t_lo (exact rank fixes the rest)
    for (int f = tid; f < n4; f += 1024) {
        float4 v = s4[f];
        #pragma unroll
        for (int j = 0; j < 4; ++j) {
            uint32_t bits = __float_as_uint(j==0 ? v.x : j==1 ? v.y : j==2 ? v.z : v.w);
            if (bits >= t_lo) {
                uint32_t pos = atomicAdd(&sh_cnt, 1u);
                if (pos < CAND_CAP)
                    cand[pos] = ((uint64_t)(~bits) << 32) | (uint64_t)(uint32_t)(4*f + j);  // ties: ASC idx
            }
        }
    }
    __syncthreads();
    uint32_t G = sh_cnt;
    if (G > CAND_CAP) G = CAND_CAP;

    // ---- exact rank (keys distinct) + decode + f32 write
    const float wy1 = window[0], wx1 = window[1], wy2 = window[2], wx2 = window[3];
    const int BK = B * KSEL;
    float* o_ai = out;             // [B,K,2] (b, idx)
    float* o_bx = out + 2 * BK;    // [B,K,4]
    float* o_cl = out + 6 * BK;
    float* o_sc = out + 7 * BK;
    float* o_vd = out + 8 * BK;

    for (uint32_t c = tid; c < G; c += 1024) {
        const uint64_t kc = cand[c];
        uint32_t r = 0;
        for (uint32_t j = 0; j < G; ++j) r += (cand[j] < kc) ? 1u : 0u;
        if (r >= KSEL) continue;

        uint32_t idx   = (uint32_t)kc;
        uint32_t sbits = ~(uint32_t)(kc >> 32);
        float score    = __uint_as_float(sbits);

        size_t base = (size_t)b * N + idx;
        const float4 a = *reinterpret_cast<const float4*>(anchors + base * 4);
        const float4 o = *reinterpret_cast<const float4*>(offsets + base * 4);

        float h  = a.z - a.x;
        float w  = a.w - a.y;
        float cy = a.x + 0.5f * h + o.x * h;
        float cx = a.y + 0.5f * w + o.y * w;
        float hh2 = h * expf(o.z);
        float ww  = w * expf(o.w);
        float y1 = fminf(fmaxf(cy - 0.5f * hh2, wy1), wy2);
        float x1 = fminf(fmaxf(cx - 0.5f * ww,  wx1), wx2);
        float y2 = fminf(fmaxf(cy + 0.5f * hh2, wy1), wy2);
        float x2 = fminf(fmaxf(cx + 0.5f * ww,  wx1), wx2);

        int ok = b * KSEL + (int)r;
        o_ai[ok*2 + 0] = (float)b;
        o_ai[ok*2 + 1] = (float)idx;
        o_bx[ok*4 + 0] = y1;
        o_bx[ok*4 + 1] = x1;
        o_bx[ok*4 + 2] = y2;
        o_bx[ok*4 + 3] = x2;
        o_cl[ok] = (float)cls_ws[base];
        o_sc[ok] = score;
        o_vd[ok] = (score > CONF_T) ? 1.0f : 0.0f;
    }
}

extern "C" void kernel_launch(void* const* d_in, const int* in_sizes, int n_in,
                              void* d_out, int out_size, void* d_ws, size_t ws_size,
                              hipStream_t stream)
{
    const float* anchors = (const float*)d_in[0];
    const float* probs   = (const float*)d_in[1];
    const float* offsets = (const float*)d_in[2];
    const float* window  = (const float*)d_in[3];

    const int B = out_size / (9 * KSEL);
    const int N = in_sizes[0] / (B * 4);
    const int total = B * N;

    float*    sc     = (float*)d_ws;
    int*      cls    = (int*)((char*)d_ws + (size_t)total * sizeof(float));
    uint32_t* hist_g = (uint32_t*)((char*)d_ws + (size_t)total * 8);

    hipMemsetAsync(hist_g, 0, (size_t)B * 2048 * sizeof(uint32_t), stream);

    hipLaunchKernelGGL(score_argmax_hist_kernel,
                       dim3((total + ROWS - 1) / ROWS), dim3(T1), 0, stream,
                       probs, sc, cls, hist_g, total, N);

    hipLaunchKernelGGL(final_select_kernel, dim3(B), dim3(1024), 0, stream,
                       sc, cls, hist_g, anchors, offsets, window,
                       (float*)d_out, N, B);
}